// Round 4
// baseline (299.783 us; speedup 1.0000x reference)
//
#include <hip/hip_runtime.h>
#include <math.h>

// Problem constants (fixed by setup_inputs: B=64, C=1, H=512, W=512 fp32)
static constexpr int Hdim = 512;
static constexpr int Wdim = 512;
static constexpr int HW   = Hdim * Wdim;       // 2^18 px per image
static constexpr int NIMG = 64;
static constexpr int WPR  = Wdim / 64;         // 8 uint64 words per row
static constexpr int TOTAL_WORDS = NIMG * Hdim * WPR;  // 262144 words (2 MB)
static constexpr int RSTRIP = 16;              // rows per block strip (main kernel)
static constexpr int SPI  = Hdim / RSTRIP;     // strips per image = 32
static constexpr int NBLK = NIMG * SPI;        // 2048 blocks
static constexpr int MROWS = RSTRIP + 4;       // strip rows + /-2 halo
static constexpr int NBLK_A = 2048;            // mask kernel blocks

// d_ws layout: [0..5] double accumulators+ticket; byte offset 4096: mask words (2 MB)
__global__ void zero_ws_kernel(double* ws) {
    if (threadIdx.x < 6) ws[threadIdx.x] = 0.0;
}

// ---- Kernel A: pack tgt>0.5 into bitmask, wave-per-word ballot ----
__global__ __launch_bounds__(256) void mask_kernel(
    const float* __restrict__ tgt, unsigned long long* __restrict__ mask)
{
    const int lane   = threadIdx.x & 63;
    const int wid    = (blockIdx.x * 256 + threadIdx.x) >> 6;
    const int nwaves = (NBLK_A * 256) >> 6;
    for (int w = wid; w < TOTAL_WORDS; w += nwaves) {
        float v = tgt[w * 64 + lane];          // coalesced 256 B per wave
        unsigned long long m = __ballot(v > 0.5f);
        if (lane == 0) mask[w] = m;
    }
}

__device__ __forceinline__ unsigned long long shl1(unsigned long long c, unsigned long long l) {
    return (c << 1) | (l >> 63);   // value at x-1
}
__device__ __forceinline__ unsigned long long shr1(unsigned long long c, unsigned long long r) {
    return (c >> 1) | (r << 63);   // value at x+1
}
__device__ __forceinline__ unsigned long long shl2(unsigned long long c, unsigned long long l) {
    return (c << 2) | (l >> 62);
}
__device__ __forceinline__ unsigned long long shr2(unsigned long long c, unsigned long long r) {
    return (c >> 2) | (r << 62);
}

// ---- Kernel B: morphology (bitwise) + elementwise math + reduction ----
__global__ __launch_bounds__(256) void combined_loss_kernel(
    const float* __restrict__ inp, const unsigned long long* __restrict__ mask,
    double* __restrict__ acc, float* __restrict__ out)
{
    __shared__ unsigned long long tmask[MROWS][WPR];   // rows r0-2 .. r0+RSTRIP+1
    __shared__ unsigned long long bmask[RSTRIP][WPR];  // boundary bits
    __shared__ float smem[4][5];

    const int img   = blockIdx.x / SPI;
    const int strip = blockIdx.x % SPI;
    const int r0    = strip * RSTRIP;
    const float* ib = inp + img * HW;
    const unsigned long long* mb = mask + img * Hdim * WPR;

    const int wave = threadIdx.x >> 6;
    const int lane = threadIdx.x & 63;

    // ---- Phase 1: load mask words for strip + halo (160 words, L2-resident) ----
    if (threadIdx.x < MROWS * WPR) {
        int row  = threadIdx.x >> 3;     // 0..19
        int word = threadIdx.x & 7;
        int gr   = r0 - 2 + row;
        unsigned long long v = 0ULL;
        if ((unsigned)gr < (unsigned)Hdim) v = mb[gr * WPR + word];
        tmask[row][word] = v;
    }
    __syncthreads();

    // ---- Phase 2: boundary = dilate2 & ~erode2 (radius-2 L1 diamond), bitwise ----
    if (threadIdx.x < RSTRIP * WPR) {
        int row  = threadIdx.x >> 3;    // strip row 0..15
        int word = threadIdx.x & 7;
        int mr = row + 2;

        #define CW(r)  tmask[r][word]
        #define LW(r)  (word > 0 ? tmask[r][word - 1] : 0ULL)
        #define RW(r)  (word < WPR - 1 ? tmask[r][word + 1] : 0ULL)
        unsigned long long c0 = CW(mr),   l0 = LW(mr),   rr0 = RW(mr);
        unsigned long long cm = CW(mr-1), lm = LW(mr-1), rm  = RW(mr-1);
        unsigned long long cp = CW(mr+1), lp = LW(mr+1), rp  = RW(mr+1);
        unsigned long long cm2 = CW(mr-2);
        unsigned long long cp2 = CW(mr+2);
        #undef CW
        #undef LW
        #undef RW

        unsigned long long er =
            c0 & shl1(c0,l0) & shr1(c0,rr0) & shl2(c0,l0) & shr2(c0,rr0)
               & cm & shl1(cm,lm) & shr1(cm,rm)
               & cp & shl1(cp,lp) & shr1(cp,rp)
               & cm2 & cp2;
        unsigned long long di =
            c0 | shl1(c0,l0) | shr1(c0,rr0) | shl2(c0,l0) | shr2(c0,rr0)
               | cm | shl1(cm,lm) | shr1(cm,rm)
               | cp | shl1(cp,lp) | shr1(cp,rp)
               | cm2 | cp2;
        bmask[row][word] = di & ~er;
    }
    __syncthreads();

    // ---- Phase 3: elementwise math, float4 over the strip ----
    float s_focal = 0.f, s_inter = 0.f, s_p = 0.f, s_bw = 0.f;
    int s_tc = 0;
    #pragma unroll
    for (int it = 0; it < (RSTRIP * Wdim) / (256 * 4); it++) {
        int flat = it * 1024 + threadIdx.x * 4;   // px within strip
        int row  = flat >> 9;
        int x    = flat & (Wdim - 1);
        const float4 f4 = *(const float4*)(ib + (r0 + row) * Wdim + x);
        unsigned int tb4 = (unsigned int)((tmask[row + 2][x >> 6] >> (x & 63)) & 0xFULL);
        unsigned int bb4 = (unsigned int)((bmask[row][x >> 6]     >> (x & 63)) & 0xFULL);
        s_tc += __popc(tb4);
        const float xs[4] = {f4.x, f4.y, f4.z, f4.w};
        #pragma unroll
        for (int k = 0; k < 4; k++) {
            float xi = xs[k];
            bool tpos = (tb4 >> k) & 1;
            float e  = __expf(-fabsf(xi));                  // exp(-|x|)
            float bce = fmaxf(xi, 0.f) - (tpos ? xi : 0.f) + __logf(1.f + e);
            float rden = __builtin_amdgcn_rcpf(1.f + e);
            float p = (xi >= 0.f ? 1.f : e) * rden;         // sigmoid
            float pt = tpos ? p : 1.f - p;                  // == exp(-bce)
            float om = 1.f - pt;
            s_focal += 0.25f * om * om * bce;
            s_p     += p;
            s_inter += tpos ? p : 0.f;
            float wgt = ((bb4 >> k) & 1) ? 6.0f : 1.0f;     // 1 + THETA*boundary
            s_bw += bce * wgt;
        }
    }
    float s_t = (float)s_tc;

    // ---- Reduce: wave shuffle -> LDS -> block atomics ----
    #pragma unroll
    for (int off = 32; off > 0; off >>= 1) {
        s_focal += __shfl_down(s_focal, off);
        s_inter += __shfl_down(s_inter, off);
        s_p     += __shfl_down(s_p,     off);
        s_t     += __shfl_down(s_t,     off);
        s_bw    += __shfl_down(s_bw,    off);
    }
    if (lane == 0) {
        smem[wave][0] = s_focal; smem[wave][1] = s_inter; smem[wave][2] = s_p;
        smem[wave][3] = s_t;     smem[wave][4] = s_bw;
    }
    __syncthreads();
    if (threadIdx.x == 0) {
        double a0 = 0, a1 = 0, a2 = 0, a3 = 0, a4 = 0;
        #pragma unroll
        for (int w = 0; w < 4; w++) {
            a0 += smem[w][0]; a1 += smem[w][1]; a2 += smem[w][2];
            a3 += smem[w][3]; a4 += smem[w][4];
        }
        atomicAdd(&acc[0], a0);
        atomicAdd(&acc[1], a1);
        atomicAdd(&acc[2], a2);
        atomicAdd(&acc[3], a3);
        atomicAdd(&acc[4], a4);
        __threadfence();
        unsigned long long ticket = atomicAdd((unsigned long long*)&acc[5], 1ULL);
        if (ticket == (unsigned long long)(gridDim.x - 1)) {
            double b0 = atomicAdd(&acc[0], 0.0);
            double b1 = atomicAdd(&acc[1], 0.0);
            double b2 = atomicAdd(&acc[2], 0.0);
            double b3 = atomicAdd(&acc[3], 0.0);
            double b4 = atomicAdd(&acc[4], 0.0);
            double invN = 1.0 / (double)(NIMG * HW);
            double focal_loss = b0 * invN;
            double dice = (2.0 * b1 + 1e-6) / (b2 + b3 + 1e-6);
            double boundary_loss = b4 * invN;
            out[0] = (float)(0.3 * focal_loss + 0.4 * (1.0 - dice) + 0.3 * boundary_loss);
        }
    }
}

extern "C" void kernel_launch(void* const* d_in, const int* in_sizes, int n_in,
                              void* d_out, int out_size, void* d_ws, size_t ws_size,
                              hipStream_t stream) {
    const float* inp = (const float*)d_in[0];
    const float* tgt = (const float*)d_in[1];
    float* out = (float*)d_out;
    double* acc = (double*)d_ws;
    unsigned long long* mask = (unsigned long long*)((char*)d_ws + 4096);

    zero_ws_kernel<<<1, 64, 0, stream>>>(acc);
    mask_kernel<<<NBLK_A, 256, 0, stream>>>(tgt, mask);
    combined_loss_kernel<<<NBLK, 256, 0, stream>>>(inp, mask, acc, out);
}

// Round 5
// 151.545 us; speedup vs baseline: 1.9782x; 1.9782x over previous
//
#include <hip/hip_runtime.h>
#include <math.h>

// Problem constants (fixed by setup_inputs: B=64, C=1, H=512, W=512 fp32)
static constexpr int Hdim = 512;
static constexpr int Wdim = 512;
static constexpr int HW   = Hdim * Wdim;       // 2^18 px per image
static constexpr int NIMG = 64;
static constexpr int WPR  = Wdim / 64;         // 8 uint64 words per row
static constexpr int TOTAL_WORDS = NIMG * Hdim * WPR;  // 262144 words (2 MB)
static constexpr int RSTRIP = 32;              // rows per block strip (main kernel)
static constexpr int SPI  = Hdim / RSTRIP;     // strips per image = 16
static constexpr int NBLK = NIMG * SPI;        // 1024 blocks
static constexpr int MROWS = RSTRIP + 4;       // strip rows + /-2 halo
static constexpr int NBLK_A = 2048;            // mask kernel blocks
static constexpr int NIT = (RSTRIP * Wdim) / (256 * 4);  // 16 phase-3 iters

// d_ws layout: [0, 32KB): per-block partials (NBLK slots x 8 floats, 5 used)
//              [64KB, 64KB+2MB): packed target bitmask
// No zero-init needed: main kernel overwrites every partial slot each call.

// ---- Kernel A: pack tgt>0.5 into bitmask, wave-per-word ballot, 4x MLP ----
__global__ __launch_bounds__(256) void mask_kernel(
    const float* __restrict__ tgt, unsigned long long* __restrict__ mask)
{
    const int lane = threadIdx.x & 63;
    const int wid  = (blockIdx.x * 256 + threadIdx.x) >> 6;   // 8192 waves
    // each wave owns 32 consecutive words, processed 4 at a time (independent loads)
    #pragma unroll
    for (int g = 0; g < 8; g++) {
        int w0 = wid * 32 + g * 4;
        float v0 = tgt[(w0 + 0) * 64 + lane];
        float v1 = tgt[(w0 + 1) * 64 + lane];
        float v2 = tgt[(w0 + 2) * 64 + lane];
        float v3 = tgt[(w0 + 3) * 64 + lane];
        unsigned long long m0 = __ballot(v0 > 0.5f);
        unsigned long long m1 = __ballot(v1 > 0.5f);
        unsigned long long m2 = __ballot(v2 > 0.5f);
        unsigned long long m3 = __ballot(v3 > 0.5f);
        if (lane == 0) {
            mask[w0 + 0] = m0;
            mask[w0 + 1] = m1;
            mask[w0 + 2] = m2;
            mask[w0 + 3] = m3;
        }
    }
}

__device__ __forceinline__ unsigned long long shl1(unsigned long long c, unsigned long long l) {
    return (c << 1) | (l >> 63);   // value at x-1
}
__device__ __forceinline__ unsigned long long shr1(unsigned long long c, unsigned long long r) {
    return (c >> 1) | (r << 63);   // value at x+1
}
__device__ __forceinline__ unsigned long long shl2(unsigned long long c, unsigned long long l) {
    return (c << 2) | (l >> 62);
}
__device__ __forceinline__ unsigned long long shr2(unsigned long long c, unsigned long long r) {
    return (c >> 2) | (r << 62);
}

// ---- Kernel B: morphology (bitwise) + elementwise math, block partials ----
__global__ __launch_bounds__(256) void combined_loss_kernel(
    const float* __restrict__ inp, const unsigned long long* __restrict__ mask,
    float* __restrict__ partials)
{
    __shared__ unsigned long long tmask[MROWS][WPR];   // rows r0-2 .. r0+RSTRIP+1
    __shared__ unsigned long long bmask[RSTRIP][WPR];  // boundary bits
    __shared__ float smem[4][5];

    const int img   = blockIdx.x / SPI;
    const int strip = blockIdx.x % SPI;
    const int r0    = strip * RSTRIP;
    const float* ib = inp + img * HW;
    const unsigned long long* mb = mask + img * Hdim * WPR;

    const int wave = threadIdx.x >> 6;
    const int lane = threadIdx.x & 63;

    // ---- Phase 1: load mask words for strip + halo (288 words, L2-resident) ----
    #pragma unroll
    for (int c = threadIdx.x; c < MROWS * WPR; c += 256) {
        int row  = c >> 3;               // 0..35
        int word = c & 7;
        int gr   = r0 - 2 + row;
        unsigned long long v = 0ULL;
        if ((unsigned)gr < (unsigned)Hdim) v = mb[gr * WPR + word];
        tmask[row][word] = v;
    }
    __syncthreads();

    // ---- Phase 2: boundary = dilate2 & ~erode2 (radius-2 L1 diamond), bitwise ----
    {
        int row  = threadIdx.x >> 3;    // strip row 0..31 (256 threads = 32x8 exactly)
        int word = threadIdx.x & 7;
        int mr = row + 2;

        #define CW(r)  tmask[r][word]
        #define LW(r)  (word > 0 ? tmask[r][word - 1] : 0ULL)
        #define RW(r)  (word < WPR - 1 ? tmask[r][word + 1] : 0ULL)
        unsigned long long c0 = CW(mr),   l0 = LW(mr),   rr0 = RW(mr);
        unsigned long long cm = CW(mr-1), lm = LW(mr-1), rm  = RW(mr-1);
        unsigned long long cp = CW(mr+1), lp = LW(mr+1), rp  = RW(mr+1);
        unsigned long long cm2 = CW(mr-2);
        unsigned long long cp2 = CW(mr+2);
        #undef CW
        #undef LW
        #undef RW

        unsigned long long er =
            c0 & shl1(c0,l0) & shr1(c0,rr0) & shl2(c0,l0) & shr2(c0,rr0)
               & cm & shl1(cm,lm) & shr1(cm,rm)
               & cp & shl1(cp,lp) & shr1(cp,rp)
               & cm2 & cp2;
        unsigned long long di =
            c0 | shl1(c0,l0) | shr1(c0,rr0) | shl2(c0,l0) | shr2(c0,rr0)
               | cm | shl1(cm,lm) | shr1(cm,rm)
               | cp | shl1(cp,lp) | shr1(cp,rp)
               | cm2 | cp2;
        bmask[row][word] = di & ~er;
    }
    __syncthreads();

    // ---- Phase 3: elementwise math, float4 + register prefetch ----
    float s_focal = 0.f, s_inter = 0.f, s_p = 0.f, s_bw = 0.f;
    int s_tc = 0;

    const float* base = ib + r0 * Wdim + threadIdx.x * 4;
    float4 cur = *(const float4*)(base);
    #pragma unroll
    for (int it = 0; it < NIT; it++) {
        float4 nxt;
        if (it + 1 < NIT) nxt = *(const float4*)(base + (it + 1) * 1024);

        int flat = it * 1024 + threadIdx.x * 4;   // px within strip
        int row  = flat >> 9;
        int x    = flat & (Wdim - 1);
        unsigned int tb4 = (unsigned int)((tmask[row + 2][x >> 6] >> (x & 63)) & 0xFULL);
        unsigned int bb4 = (unsigned int)((bmask[row][x >> 6]     >> (x & 63)) & 0xFULL);
        s_tc += __popc(tb4);
        const float xs[4] = {cur.x, cur.y, cur.z, cur.w};
        #pragma unroll
        for (int k = 0; k < 4; k++) {
            float xi = xs[k];
            bool tpos = (tb4 >> k) & 1;
            float e  = __expf(-fabsf(xi));                  // exp(-|x|)
            float bce = fmaxf(xi, 0.f) - (tpos ? xi : 0.f) + __logf(1.f + e);
            float rden = __builtin_amdgcn_rcpf(1.f + e);
            float p = (xi >= 0.f ? 1.f : e) * rden;         // sigmoid
            float pt = tpos ? p : 1.f - p;                  // == exp(-bce)
            float om = 1.f - pt;
            s_focal += 0.25f * om * om * bce;
            s_p     += p;
            s_inter += tpos ? p : 0.f;
            float wgt = ((bb4 >> k) & 1) ? 6.0f : 1.0f;     // 1 + THETA*boundary
            s_bw += bce * wgt;
        }
        cur = nxt;
    }
    float s_t = (float)s_tc;

    // ---- Reduce: wave shuffle -> LDS -> per-block partial store (NO atomics) ----
    #pragma unroll
    for (int off = 32; off > 0; off >>= 1) {
        s_focal += __shfl_down(s_focal, off);
        s_inter += __shfl_down(s_inter, off);
        s_p     += __shfl_down(s_p,     off);
        s_t     += __shfl_down(s_t,     off);
        s_bw    += __shfl_down(s_bw,    off);
    }
    if (lane == 0) {
        smem[wave][0] = s_focal; smem[wave][1] = s_inter; smem[wave][2] = s_p;
        smem[wave][3] = s_t;     smem[wave][4] = s_bw;
    }
    __syncthreads();
    if (threadIdx.x < 5) {
        float a = smem[0][threadIdx.x] + smem[1][threadIdx.x]
                + smem[2][threadIdx.x] + smem[3][threadIdx.x];
        partials[blockIdx.x * 8 + threadIdx.x] = a;
    }
}

// ---- Kernel C: reduce 1024 partial slots, compute final scalar ----
__global__ __launch_bounds__(256) void finalize_kernel(
    const float* __restrict__ partials, float* __restrict__ out)
{
    __shared__ float smem[4][5];
    float a0 = 0.f, a1 = 0.f, a2 = 0.f, a3 = 0.f, a4 = 0.f;
    for (int b = threadIdx.x; b < NBLK; b += 256) {
        const float* s = partials + b * 8;
        a0 += s[0]; a1 += s[1]; a2 += s[2]; a3 += s[3]; a4 += s[4];
    }
    #pragma unroll
    for (int off = 32; off > 0; off >>= 1) {
        a0 += __shfl_down(a0, off);
        a1 += __shfl_down(a1, off);
        a2 += __shfl_down(a2, off);
        a3 += __shfl_down(a3, off);
        a4 += __shfl_down(a4, off);
    }
    int wave = threadIdx.x >> 6;
    int lane = threadIdx.x & 63;
    if (lane == 0) {
        smem[wave][0] = a0; smem[wave][1] = a1; smem[wave][2] = a2;
        smem[wave][3] = a3; smem[wave][4] = a4;
    }
    __syncthreads();
    if (threadIdx.x == 0) {
        double b0 = 0, b1 = 0, b2 = 0, b3 = 0, b4 = 0;
        #pragma unroll
        for (int w = 0; w < 4; w++) {
            b0 += smem[w][0]; b1 += smem[w][1]; b2 += smem[w][2];
            b3 += smem[w][3]; b4 += smem[w][4];
        }
        double invN = 1.0 / (double)(NIMG * HW);
        double focal_loss = b0 * invN;
        double dice = (2.0 * b1 + 1e-6) / (b2 + b3 + 1e-6);
        double boundary_loss = b4 * invN;
        out[0] = (float)(0.3 * focal_loss + 0.4 * (1.0 - dice) + 0.3 * boundary_loss);
    }
}

extern "C" void kernel_launch(void* const* d_in, const int* in_sizes, int n_in,
                              void* d_out, int out_size, void* d_ws, size_t ws_size,
                              hipStream_t stream) {
    const float* inp = (const float*)d_in[0];
    const float* tgt = (const float*)d_in[1];
    float* out = (float*)d_out;
    float* partials = (float*)d_ws;
    unsigned long long* mask = (unsigned long long*)((char*)d_ws + 65536);

    mask_kernel<<<NBLK_A, 256, 0, stream>>>(tgt, mask);
    combined_loss_kernel<<<NBLK, 256, 0, stream>>>(inp, mask, partials);
    finalize_kernel<<<1, 256, 0, stream>>>(partials, out);
}